// Round 9
// baseline (784.221 us; speedup 1.0000x reference)
//
#include <hip/hip_runtime.h>
#include <cstdint>
#include <cstddef>

typedef _Float16 f16x8 __attribute__((ext_vector_type(8)));
typedef float f32x4 __attribute__((ext_vector_type(4)));

#define NTOK 16384
#define DIMV 512
#define KCODE 4096

// output layout (float32): z_q_st | indices | vq_loss | perplexity
#define IDX_OFF (NTOK * DIMV)
#define LOSSO   (IDX_OFF + NTOK)
#define PERPO   (LOSSO + 1)

// workspace layout
static const size_t A2_OFF = 0;                                   // fp16 256*z   [NTOK][512]
static const size_t B2_OFF = A2_OFF + (size_t)NTOK * DIMV * 2;    // fp16 256*e   [KCODE][512]
static const size_t EN_OFF = B2_OFF + (size_t)KCODE * DIMV * 2;   // f32 C32 = np-pairwise ||e||^2
static const size_t RK_OFF = EN_OFF + (size_t)KCODE * 4;          // u32 [NTOK][16 tiles][2] top-2 keys
static const size_t CNT_OFF = RK_OFF + (size_t)NTOK * 32 * 4;     // u32 [KCODE]
static const size_t LP_OFF  = CNT_OFF + (size_t)KCODE * 4;        // f64 [64] loss partials
static const size_t DONE_OFF = LP_OFF + 64 * 8;                   // u32 done counter

// fp32 square with contraction barrier (mimic numpy's separate multiply+add)
__device__ __forceinline__ float sqf(float v) {
    float p = v * v;
    asm volatile("" : "+v"(p));
    return p;
}

// numpy pairwise sum of squares of a 512-elem LDS row (verified r3-r8).
__device__ __forceinline__ float np_pairwise_sq(const float* xs, int t) {
    float accp = 0.0f;
    if (t < 32) {
        const float* blk = xs + (t >> 3) * 128;
        int j = t & 7;
        float rj = sqf(blk[j]);
#pragma unroll
        for (int tt = 1; tt < 16; ++tt) rj += sqf(blk[tt * 8 + j]);
        accp = rj;
    }
#pragma unroll
    for (int d = 1; d <= 16; d <<= 1) accp += __shfl_xor(accp, d, 64);
    return __shfl(accp, 0, 64);
}

// ---------------- fused prep: z->fp16, embed->fp16 + C32 + zero counts/lossPart/done
__global__ void prep_k(const float* __restrict__ z, const float* __restrict__ e,
                       _Float16* __restrict__ A2, _Float16* __restrict__ B2,
                       float* __restrict__ C32, unsigned* __restrict__ counts,
                       double* __restrict__ lossPart, unsigned* __restrict__ done) {
    __shared__ float es[4][512];
    const int b = blockIdx.x;
    if (b < 4096) {                       // z: 4 rows per block
        int t = b * 256 + threadIdx.x;
        int n = t >> 6;
        int dc = (t & 63) << 3;
        const float* zp = z + (size_t)n * DIMV + dc;
        float4 v0 = ((const float4*)zp)[0];
        float4 v1 = ((const float4*)zp)[1];
        float vs[8] = {v0.x, v0.y, v0.z, v0.w, v1.x, v1.y, v1.z, v1.w};
        f16x8 hi;
#pragma unroll
        for (int i = 0; i < 8; ++i) hi[i] = (_Float16)(vs[i] * 256.0f);
        *(f16x8*)(A2 + (size_t)n * DIMV + dc) = hi;
    } else {                              // embed: 4 rows per block, 1 wave/row
        const int wv = threadIdx.x >> 6, t = threadIdx.x & 63;
        const int k = (b - 4096) * 4 + wv;
        const float* ep = e + (size_t)k * DIMV + t * 8;
        float4 v0 = ((const float4*)ep)[0];
        float4 v1 = ((const float4*)ep)[1];
        ((float4*)es[wv])[t * 2] = v0;
        ((float4*)es[wv])[t * 2 + 1] = v1;
        float vs[8] = {v0.x, v0.y, v0.z, v0.w, v1.x, v1.y, v1.z, v1.w};
        f16x8 hi;
#pragma unroll
        for (int i = 0; i < 8; ++i) hi[i] = (_Float16)(vs[i] * 256.0f);
        *(f16x8*)(B2 + (size_t)k * DIMV + t * 8) = hi;
        float c = np_pairwise_sq(es[wv], t);
        if (t == 0) C32[k] = c;
        if (threadIdx.x < 4) counts[(b - 4096) * 4 + threadIdx.x] = 0u;
        if (b == 4096) {                  // one block zeroes the reduction state
            if (threadIdx.x < 64) lossPart[threadIdx.x] = 0.0;
            if (threadIdx.x == 64) *done = 0u;
        }
    }
}

// ---------------- async global->LDS 16B
typedef uint32_t __attribute__((address_space(1))) gas_u32;
typedef uint32_t __attribute__((address_space(3))) las_u32;
__device__ __forceinline__ void g2l16(const _Float16* g, _Float16* l) {
    __builtin_amdgcn_global_load_lds((const gas_u32*)(uintptr_t)g,
                                     (las_u32*)(uint32_t)(uintptr_t)l, 16, 0, 0);
}

__device__ __forceinline__ void top2_merge32(unsigned& k1, unsigned& k2,
                                             unsigned o1, unsigned o2) {
    unsigned n1 = k1 < o1 ? k1 : o1;
    unsigned mx = k1 < o1 ? o1 : k1;
    unsigned n2 = k2 < o2 ? k2 : o2;
    k1 = n1;
    k2 = mx < n2 ? mx : n2;
}

// DPP row_shr top-2 reduction stage (pure VALU, no DS pipe).
// row_shr:N moves lane i-N -> lane i: merge ACCUMULATES TOWARD LANE 15 of each
// 16-lane row; out-of-row sources take old = -1 (identity for min).
#define DPP_TOP2(CTRL)                                                                     \
    {                                                                                      \
        unsigned o1 = (unsigned)__builtin_amdgcn_update_dpp(-1, (int)k1, CTRL, 0xF, 0xF, false); \
        unsigned o2 = (unsigned)__builtin_amdgcn_update_dpp(-1, (int)k2, CTRL, 0xF, 0xF, false); \
        top2_merge32(k1, k2, o1, o2);                                                      \
    }

// ---------------- GEMM (K=512 fp16, 128x256 tile, 8 waves) + per-tile top-2
__global__ __launch_bounds__(512) void gemm_top2_k(
    const _Float16* __restrict__ A2, const _Float16* __restrict__ B2,
    const float* __restrict__ C32, unsigned* __restrict__ rk2) {
    __shared__ _Float16 lA[128 * 64];   // 16 KB (reused for epilogue merge)
    __shared__ _Float16 lB[256 * 64];   // 32 KB
    const int nt = blockIdx.x;     // 16 code tiles of 256
    const int mt = blockIdx.y;     // 128 row tiles of 128
    const int tid = threadIdx.x;
    const int w = tid >> 6, l = tid & 63;
    const int wm = w & 1, wn = w >> 1;   // 2 x 4 wave grid, each wave 64x64

    // staging: lane l loads 16B; row = l>>3, chunk = l&7, XOR-swizzled source
    const int srow = l >> 3, schunk = l & 7;
    const int gch = (schunk ^ srow) << 3;
    const _Float16* aG = A2 + (size_t)(mt * 128 + w * 16 + srow) * DIMV + gch;
    const _Float16* bG = B2 + (size_t)(nt * 256 + w * 32 + srow) * DIMV + gch;
    _Float16* aL = &lA[(w * 16) * 64];
    _Float16* bL = &lB[(w * 32) * 64];

    const int lane15 = l & 15, q = l >> 4, sx = l & 7;
    const int aRow = (wm * 64 + lane15) * 64;
    const int bRow = (wn * 64 + lane15) * 64;

    f32x4 acc[4][4] = {};

    for (int kt = 0; kt < 8; ++kt) {
        const _Float16* ag = aG + kt * 64;
        const _Float16* bg = bG + kt * 64;
#pragma unroll
        for (int r = 0; r < 2; ++r) g2l16(ag + (size_t)r * 8 * DIMV, aL + r * 512);
#pragma unroll
        for (int r = 0; r < 4; ++r) g2l16(bg + (size_t)r * 8 * DIMV, bL + r * 512);
        __syncthreads();

#pragma unroll
        for (int kk2 = 0; kk2 < 2; ++kk2) {
            f16x8 af[4], bf[4];
            const int ch = ((kk2 * 4 + q) ^ sx) << 3;
#pragma unroll
            for (int i = 0; i < 4; ++i) {
                af[i] = *(const f16x8*)&lA[aRow + i * 1024 + ch];
                bf[i] = *(const f16x8*)&lB[bRow + i * 1024 + ch];
            }
#pragma unroll
            for (int i = 0; i < 4; ++i)
#pragma unroll
                for (int j = 0; j < 4; ++j)
                    acc[i][j] = __builtin_amdgcn_mfma_f32_16x16x32_f16(af[i], bf[j], acc[i][j], 0, 0, 0);
        }
        __syncthreads();
    }

    // epilogue: dist = 65536*C32 - 2*acc + BIAS (4e6 > |range|): positive => raw
    // IEEE bits monotone; truncate to 24 bits, pack tile-col in low byte.
    unsigned* lk32 = (unsigned*)lA;    // [128 rows][stride 10]: 4 wn-slots x 2
    const int colL = wn * 64 + lane15;               // 0..255
    float envals[4];
#pragma unroll
    for (int j = 0; j < 4; ++j) envals[j] = C32[nt * 256 + colL + j * 16] * 65536.0f + 4.0e6f;

#pragma unroll
    for (int i = 0; i < 4; ++i) {
#pragma unroll
        for (int rr = 0; rr < 4; ++rr) {
            unsigned k1 = 0xFFFFFFFFu, k2 = 0xFFFFFFFFu;
#pragma unroll
            for (int j = 0; j < 4; ++j) {
                float dist = envals[j] - 2.0f * acc[i][j][rr];
                unsigned key = (__float_as_uint(dist) & 0xFFFFFF00u) | (unsigned)(colL + j * 16);
                if (key < k1) { k2 = k1; k1 = key; } else if (key < k2) k2 = key;
            }
            DPP_TOP2(0x118)   // row_shr:8
            DPP_TOP2(0x114)   // row_shr:4
            DPP_TOP2(0x112)   // row_shr:2
            DPP_TOP2(0x111)   // row_shr:1  -> LANE 15 of each 16 has row top-2
            if (lane15 == 15) {
                int rl = wm * 64 + i * 16 + q * 4 + rr;
                lk32[rl * 10 + wn * 2]     = k1;
                lk32[rl * 10 + wn * 2 + 1] = k2;
            }
        }
    }
    __syncthreads();
    if (tid < 128) {
        unsigned a1 = lk32[tid * 10], a2 = lk32[tid * 10 + 1];
#pragma unroll
        for (int p = 1; p < 4; ++p)
            top2_merge32(a1, a2, lk32[tid * 10 + p * 2], lk32[tid * 10 + p * 2 + 1]);
        size_t base = (size_t)(mt * 128 + tid) * 32 + nt * 2;
        rk2[base] = a1;
        rk2[base + 1] = a2;
    }
}

// ---------------- refine: np-fp32-semantics over approx-top-4, winner via LDS
// broadcast; per-block loss atomic into 64 slots; LAST block computes scalars.
__global__ __launch_bounds__(256) void refine_k(
    const unsigned* __restrict__ rk2,
    const float* __restrict__ embed, const float* __restrict__ z,
    const float* __restrict__ C32,
    float* __restrict__ out, unsigned* __restrict__ counts,
    double* __restrict__ lossPart, unsigned* __restrict__ done) {
    __shared__ float zs[4][512];
    __shared__ float zqs[4][512];
    __shared__ double lsh[4];
    __shared__ unsigned oldsh;
    const int wv = threadIdx.x >> 6, t = threadIdx.x & 63;
    const int r = blockIdx.x * 4 + wv;
    const float4* zp = (const float4*)(z + (size_t)r * DIMV);
    float4 za = zp[t * 2], zb = zp[t * 2 + 1];
    ((float4*)zs[wv])[t * 2] = za;
    ((float4*)zs[wv])[t * 2 + 1] = zb;
    __syncthreads();

    // np-exact A = np.sum(z*z, axis=1)
    float A32 = np_pairwise_sq(zs[wv], t);

    // rebuild unique u64 work keys (biased-dist24 | global col) from u32 keys
    unsigned long long key = ~0ull;
    if (t < 32) {
        unsigned kraw = rk2[(size_t)r * 32 + t];
        unsigned col = (unsigned)(t >> 1) * 256u + (kraw & 255u);
        key = ((unsigned long long)(kraw & 0xFFFFFF00u) << 32) | col;
    }

    // extract approx top-4; 16-lane group g keeps candidate #g
    const int g = t >> 4, j = t & 15;
    unsigned mycand = 0;
#pragma unroll
    for (int c = 0; c < 4; ++c) {
        unsigned long long m = key;
#pragma unroll
        for (int d = 1; d < 64; d <<= 1) {
            unsigned long long o = __shfl_xor(m, d, 64);
            m = o < m ? o : m;
        }
        if (c == g) mycand = (unsigned)(m & 0xFFFFFFFFull);
        if (key == m) key = ~0ull;   // keys unique (global col in low bits)
    }

    // parallel scoring: group g computes B = z . e_mycand in fp64; keep e vals
    const float4* ep = (const float4*)(embed + (size_t)mycand * DIMV);
    float4 ev[8];
    double s = 0.0;
#pragma unroll
    for (int it = 0; it < 8; ++it) {
        float4 e4 = ep[j + it * 16];
        ev[it] = e4;
        float4 z4 = ((const float4*)zs[wv])[j + it * 16];
        s += (double)z4.x * e4.x + (double)z4.y * e4.y +
             (double)z4.z * e4.z + (double)z4.w * e4.w;
    }
#pragma unroll
    for (int d = 1; d < 16; d <<= 1) s += __shfl_xor(s, d, 64);   // group sum

    // np rounding grid: d = fl(fl(A - 2B) + C)
    float Bf = (float)s;
    float d32 = (A32 - 2.0f * Bf) + C32[mycand];
    unsigned u = __float_as_uint(d32);
    u = (u & 0x80000000u) ? ~u : (u | 0x80000000u);
    unsigned long long dk = ((unsigned long long)u << 32) | mycand;
#pragma unroll
    for (int d = 16; d < 64; d <<= 1) {                           // cross-group argmin
        unsigned long long o = __shfl_xor(dk, d, 64);
        dk = o < dk ? o : dk;
    }
    const unsigned ibest = (unsigned)(dk & 0xFFFFFFFFull);

    // winner broadcast: winning group's registers -> LDS (candidates unique,
    // exactly one group matches)
    if (mycand == ibest) {
#pragma unroll
        for (int it = 0; it < 8; ++it) ((float4*)zqs[wv])[j + it * 16] = ev[it];
    }
    __syncthreads();   // order LDS writes before reads (also covers lsh below)

    float4 wa = ((const float4*)zqs[wv])[t * 2];
    float4 wb = ((const float4*)zqs[wv])[t * 2 + 1];
    float4* op = (float4*)(out + (size_t)r * DIMV);
    op[t * 2] = wa;
    op[t * 2 + 1] = wb;
    double dx0 = (double)za.x - wa.x, dx1 = (double)za.y - wa.y;
    double dx2 = (double)za.z - wa.z, dx3 = (double)za.w - wa.w;
    double dx4 = (double)zb.x - wb.x, dx5 = (double)zb.y - wb.y;
    double dx6 = (double)zb.z - wb.z, dx7 = (double)zb.w - wb.w;
    double ls = dx0 * dx0 + dx1 * dx1 + dx2 * dx2 + dx3 * dx3 +
                dx4 * dx4 + dx5 * dx5 + dx6 * dx6 + dx7 * dx7;
#pragma unroll
    for (int d = 1; d < 64; d <<= 1) ls += __shfl_xor(ls, d, 64);
    if (t == 0) {
        out[IDX_OFF + r] = (float)ibest;
        lsh[wv] = ls;
        atomicAdd(&counts[ibest], 1u);
        __threadfence();
    }
    __syncthreads();
    if (threadIdx.x == 0) {
        double bsum = lsh[0] + lsh[1] + lsh[2] + lsh[3];
        atomicAdd(&lossPart[blockIdx.x & 63], bsum);
        __threadfence();
        oldsh = atomicAdd(done, 1u);
    }
    __syncthreads();

    if (oldsh == 4095u) {   // last block: final scalar reduction
        __threadfence();
        int tt = threadIdx.x;
        double lt = (tt < 64) ? atomicAdd(&lossPart[tt], 0.0) : 0.0;
#pragma unroll
        for (int d = 1; d < 64; d <<= 1) lt += __shfl_xor(lt, d, 64);
        float sent = 0.0f;
        for (int i = tt; i < KCODE; i += 256) {
            unsigned c = atomicAdd(&counts[i], 0u);
            float p = (float)c * (1.0f / (float)NTOK);
            sent += p * logf(p + 1e-10f);
        }
#pragma unroll
        for (int d = 1; d < 64; d <<= 1) sent += __shfl_xor(sent, d, 64);
        __shared__ float fred[4];
        __shared__ double dred[4];
        if ((tt & 63) == 0) { fred[tt >> 6] = sent; dred[tt >> 6] = lt; }
        __syncthreads();
        if (tt == 0) {
            float stot = fred[0] + fred[1] + fred[2] + fred[3];
            double ltot = dred[0];   // only wave 0 had lossPart data
            out[PERPO] = expf(-stot);
            out[LOSSO] = 0.25f * (float)(ltot * (1.0 / (double)(NTOK * DIMV)));
        }
    }
}

extern "C" void kernel_launch(void* const* d_in, const int* in_sizes, int n_in,
                              void* d_out, int out_size, void* d_ws, size_t ws_size,
                              hipStream_t stream) {
    const float* z     = (const float*)d_in[0];
    const float* embed = (const float*)d_in[1];
    float* out = (float*)d_out;
    char* ws = (char*)d_ws;

    _Float16* A2 = (_Float16*)(ws + A2_OFF);
    _Float16* B2 = (_Float16*)(ws + B2_OFF);
    float* C32 = (float*)(ws + EN_OFF);
    unsigned* rk2 = (unsigned*)(ws + RK_OFF);
    unsigned* counts = (unsigned*)(ws + CNT_OFF);
    double* lossPart = (double*)(ws + LP_OFF);
    unsigned* done = (unsigned*)(ws + DONE_OFF);

    prep_k<<<5120, 256, 0, stream>>>(z, embed, A2, B2, C32, counts, lossPart, done);
    gemm_top2_k<<<dim3(16, 128), 512, 0, stream>>>(A2, B2, C32, rk2);
    refine_k<<<NTOK / 4, 256, 0, stream>>>(rk2, embed, z, C32, out, counts, lossPart, done);
}

// Round 10
// 209.690 us; speedup vs baseline: 3.7399x; 3.7399x over previous
//
#include <hip/hip_runtime.h>
#include <cstdint>
#include <cstddef>

typedef _Float16 f16x8 __attribute__((ext_vector_type(8)));
typedef float f32x4 __attribute__((ext_vector_type(4)));

#define NTOK 16384
#define DIMV 512
#define KCODE 4096

// output layout (float32): z_q_st | indices | vq_loss | perplexity
#define IDX_OFF (NTOK * DIMV)
#define LOSSO   (IDX_OFF + NTOK)
#define PERPO   (LOSSO + 1)

// workspace layout
static const size_t A2_OFF = 0;                                   // fp16 256*z   [NTOK][512]
static const size_t B2_OFF = A2_OFF + (size_t)NTOK * DIMV * 2;    // fp16 256*e   [KCODE][512]
static const size_t EN_OFF = B2_OFF + (size_t)KCODE * DIMV * 2;   // f32 C32 = np-pairwise ||e||^2
static const size_t RK_OFF = EN_OFF + (size_t)KCODE * 4;          // u32 [NTOK][16 tiles][2] top-2 keys
static const size_t CNT_OFF = RK_OFF + (size_t)NTOK * 32 * 4;     // u32 [KCODE]
static const size_t RLOSS_OFF = CNT_OFF + (size_t)KCODE * 4;      // f64 [NTOK] per-row loss

// fp32 square with contraction barrier (mimic numpy's separate multiply+add)
__device__ __forceinline__ float sqf(float v) {
    float p = v * v;
    asm volatile("" : "+v"(p));
    return p;
}

// numpy pairwise sum of squares of a 512-elem LDS row (verified r3-r8).
__device__ __forceinline__ float np_pairwise_sq(const float* xs, int t) {
    float accp = 0.0f;
    if (t < 32) {
        const float* blk = xs + (t >> 3) * 128;
        int j = t & 7;
        float rj = sqf(blk[j]);
#pragma unroll
        for (int tt = 1; tt < 16; ++tt) rj += sqf(blk[tt * 8 + j]);
        accp = rj;
    }
#pragma unroll
    for (int d = 1; d <= 16; d <<= 1) accp += __shfl_xor(accp, d, 64);
    return __shfl(accp, 0, 64);
}

// ---------------- fused prep: z->fp16, embed->fp16 + C32 + zero counts
__global__ void prep_k(const float* __restrict__ z, const float* __restrict__ e,
                       _Float16* __restrict__ A2, _Float16* __restrict__ B2,
                       float* __restrict__ C32, unsigned* __restrict__ counts) {
    __shared__ float es[4][512];
    const int b = blockIdx.x;
    if (b < 4096) {                       // z: 4 rows per block
        int t = b * 256 + threadIdx.x;
        int n = t >> 6;
        int dc = (t & 63) << 3;
        const float* zp = z + (size_t)n * DIMV + dc;
        float4 v0 = ((const float4*)zp)[0];
        float4 v1 = ((const float4*)zp)[1];
        float vs[8] = {v0.x, v0.y, v0.z, v0.w, v1.x, v1.y, v1.z, v1.w};
        f16x8 hi;
#pragma unroll
        for (int i = 0; i < 8; ++i) hi[i] = (_Float16)(vs[i] * 256.0f);
        *(f16x8*)(A2 + (size_t)n * DIMV + dc) = hi;
    } else {                              // embed: 4 rows per block, 1 wave/row
        const int wv = threadIdx.x >> 6, t = threadIdx.x & 63;
        const int k = (b - 4096) * 4 + wv;
        const float* ep = e + (size_t)k * DIMV + t * 8;
        float4 v0 = ((const float4*)ep)[0];
        float4 v1 = ((const float4*)ep)[1];
        ((float4*)es[wv])[t * 2] = v0;
        ((float4*)es[wv])[t * 2 + 1] = v1;
        float vs[8] = {v0.x, v0.y, v0.z, v0.w, v1.x, v1.y, v1.z, v1.w};
        f16x8 hi;
#pragma unroll
        for (int i = 0; i < 8; ++i) hi[i] = (_Float16)(vs[i] * 256.0f);
        *(f16x8*)(B2 + (size_t)k * DIMV + t * 8) = hi;
        float c = np_pairwise_sq(es[wv], t);
        if (t == 0) C32[k] = c;
        if (threadIdx.x < 4) counts[(b - 4096) * 4 + threadIdx.x] = 0u;
    }
}

// ---------------- async global->LDS 16B
typedef uint32_t __attribute__((address_space(1))) gas_u32;
typedef uint32_t __attribute__((address_space(3))) las_u32;
__device__ __forceinline__ void g2l16(const _Float16* g, _Float16* l) {
    __builtin_amdgcn_global_load_lds((const gas_u32*)(uintptr_t)g,
                                     (las_u32*)(uint32_t)(uintptr_t)l, 16, 0, 0);
}

__device__ __forceinline__ void top2_merge32(unsigned& k1, unsigned& k2,
                                             unsigned o1, unsigned o2) {
    unsigned n1 = k1 < o1 ? k1 : o1;
    unsigned mx = k1 < o1 ? o1 : k1;
    unsigned n2 = k2 < o2 ? k2 : o2;
    k1 = n1;
    k2 = mx < n2 ? mx : n2;
}

// DPP row_shr top-2 reduction stage (pure VALU, no DS pipe).
// row_shr:N moves lane i-N -> lane i: merge ACCUMULATES TOWARD LANE 15 of each
// 16-lane row; out-of-row sources take old = -1 (identity for min).
#define DPP_TOP2(CTRL)                                                                     \
    {                                                                                      \
        unsigned o1 = (unsigned)__builtin_amdgcn_update_dpp(-1, (int)k1, CTRL, 0xF, 0xF, false); \
        unsigned o2 = (unsigned)__builtin_amdgcn_update_dpp(-1, (int)k2, CTRL, 0xF, 0xF, false); \
        top2_merge32(k1, k2, o1, o2);                                                      \
    }

// ---------------- GEMM (K=512 fp16, 128x256 tile, 8 waves) + per-tile top-2
__global__ __launch_bounds__(512) void gemm_top2_k(
    const _Float16* __restrict__ A2, const _Float16* __restrict__ B2,
    const float* __restrict__ C32, unsigned* __restrict__ rk2) {
    __shared__ _Float16 lA[128 * 64];   // 16 KB (reused for epilogue merge)
    __shared__ _Float16 lB[256 * 64];   // 32 KB
    const int nt = blockIdx.x;     // 16 code tiles of 256
    const int mt = blockIdx.y;     // 128 row tiles of 128
    const int tid = threadIdx.x;
    const int w = tid >> 6, l = tid & 63;
    const int wm = w & 1, wn = w >> 1;   // 2 x 4 wave grid, each wave 64x64

    // staging: lane l loads 16B; row = l>>3, chunk = l&7, XOR-swizzled source
    const int srow = l >> 3, schunk = l & 7;
    const int gch = (schunk ^ srow) << 3;
    const _Float16* aG = A2 + (size_t)(mt * 128 + w * 16 + srow) * DIMV + gch;
    const _Float16* bG = B2 + (size_t)(nt * 256 + w * 32 + srow) * DIMV + gch;
    _Float16* aL = &lA[(w * 16) * 64];
    _Float16* bL = &lB[(w * 32) * 64];

    const int lane15 = l & 15, q = l >> 4, sx = l & 7;
    const int aRow = (wm * 64 + lane15) * 64;
    const int bRow = (wn * 64 + lane15) * 64;

    f32x4 acc[4][4] = {};

    for (int kt = 0; kt < 8; ++kt) {
        const _Float16* ag = aG + kt * 64;
        const _Float16* bg = bG + kt * 64;
#pragma unroll
        for (int r = 0; r < 2; ++r) g2l16(ag + (size_t)r * 8 * DIMV, aL + r * 512);
#pragma unroll
        for (int r = 0; r < 4; ++r) g2l16(bg + (size_t)r * 8 * DIMV, bL + r * 512);
        __syncthreads();

#pragma unroll
        for (int kk2 = 0; kk2 < 2; ++kk2) {
            f16x8 af[4], bf[4];
            const int ch = ((kk2 * 4 + q) ^ sx) << 3;
#pragma unroll
            for (int i = 0; i < 4; ++i) {
                af[i] = *(const f16x8*)&lA[aRow + i * 1024 + ch];
                bf[i] = *(const f16x8*)&lB[bRow + i * 1024 + ch];
            }
#pragma unroll
            for (int i = 0; i < 4; ++i)
#pragma unroll
                for (int j = 0; j < 4; ++j)
                    acc[i][j] = __builtin_amdgcn_mfma_f32_16x16x32_f16(af[i], bf[j], acc[i][j], 0, 0, 0);
        }
        __syncthreads();
    }

    // epilogue: dist = 65536*C32 - 2*acc + BIAS (4e6 > |range|): positive => raw
    // IEEE bits monotone; truncate to 24 bits, pack tile-col in low byte.
    unsigned* lk32 = (unsigned*)lA;    // [128 rows][stride 10]: 4 wn-slots x 2
    const int colL = wn * 64 + lane15;               // 0..255
    float envals[4];
#pragma unroll
    for (int j = 0; j < 4; ++j) envals[j] = C32[nt * 256 + colL + j * 16] * 65536.0f + 4.0e6f;

#pragma unroll
    for (int i = 0; i < 4; ++i) {
#pragma unroll
        for (int rr = 0; rr < 4; ++rr) {
            unsigned k1 = 0xFFFFFFFFu, k2 = 0xFFFFFFFFu;
#pragma unroll
            for (int j = 0; j < 4; ++j) {
                float dist = envals[j] - 2.0f * acc[i][j][rr];
                unsigned key = (__float_as_uint(dist) & 0xFFFFFF00u) | (unsigned)(colL + j * 16);
                if (key < k1) { k2 = k1; k1 = key; } else if (key < k2) k2 = key;
            }
            DPP_TOP2(0x118)   // row_shr:8
            DPP_TOP2(0x114)   // row_shr:4
            DPP_TOP2(0x112)   // row_shr:2
            DPP_TOP2(0x111)   // row_shr:1  -> LANE 15 of each 16 has row top-2
            if (lane15 == 15) {
                int rl = wm * 64 + i * 16 + q * 4 + rr;
                lk32[rl * 10 + wn * 2]     = k1;
                lk32[rl * 10 + wn * 2 + 1] = k2;
            }
        }
    }
    __syncthreads();
    if (tid < 128) {
        unsigned a1 = lk32[tid * 10], a2 = lk32[tid * 10 + 1];
#pragma unroll
        for (int p = 1; p < 4; ++p)
            top2_merge32(a1, a2, lk32[tid * 10 + p * 2], lk32[tid * 10 + p * 2 + 1]);
        size_t base = (size_t)(mt * 128 + tid) * 32 + nt * 2;
        rk2[base] = a1;
        rk2[base + 1] = a2;
    }
}

// ---------------- refine: np-fp32-semantics over approx-top-4 of 32 candidates;
// winner z_q via LDS broadcast from the winning group's registers. NO fences.
__global__ __launch_bounds__(256) void refine_k(
    const unsigned* __restrict__ rk2,
    const float* __restrict__ embed, const float* __restrict__ z,
    const float* __restrict__ C32,
    float* __restrict__ out, unsigned* __restrict__ counts,
    double* __restrict__ rloss) {
    __shared__ float zs[4][512];
    __shared__ float zqs[4][512];
    const int wv = threadIdx.x >> 6, t = threadIdx.x & 63;
    const int r = blockIdx.x * 4 + wv;
    const float4* zp = (const float4*)(z + (size_t)r * DIMV);
    float4 za = zp[t * 2], zb = zp[t * 2 + 1];
    ((float4*)zs[wv])[t * 2] = za;
    ((float4*)zs[wv])[t * 2 + 1] = zb;
    __syncthreads();

    // np-exact A = np.sum(z*z, axis=1)
    float A32 = np_pairwise_sq(zs[wv], t);

    // rebuild unique u64 work keys (biased-dist24 | global col) from u32 keys
    unsigned long long key = ~0ull;
    if (t < 32) {
        unsigned kraw = rk2[(size_t)r * 32 + t];
        unsigned col = (unsigned)(t >> 1) * 256u + (kraw & 255u);
        key = ((unsigned long long)(kraw & 0xFFFFFF00u) << 32) | col;
    }

    // extract approx top-4; 16-lane group g keeps candidate #g
    const int g = t >> 4, j = t & 15;
    unsigned mycand = 0;
#pragma unroll
    for (int c = 0; c < 4; ++c) {
        unsigned long long m = key;
#pragma unroll
        for (int d = 1; d < 64; d <<= 1) {
            unsigned long long o = __shfl_xor(m, d, 64);
            m = o < m ? o : m;
        }
        if (c == g) mycand = (unsigned)(m & 0xFFFFFFFFull);
        if (key == m) key = ~0ull;   // keys unique (global col in low bits)
    }

    // parallel scoring: group g computes B = z . e_mycand in fp64; keep e vals
    const float4* ep = (const float4*)(embed + (size_t)mycand * DIMV);
    float4 ev[8];
    double s = 0.0;
#pragma unroll
    for (int it = 0; it < 8; ++it) {
        float4 e4 = ep[j + it * 16];
        ev[it] = e4;
        float4 z4 = ((const float4*)zs[wv])[j + it * 16];
        s += (double)z4.x * e4.x + (double)z4.y * e4.y +
             (double)z4.z * e4.z + (double)z4.w * e4.w;
    }
#pragma unroll
    for (int d = 1; d < 16; d <<= 1) s += __shfl_xor(s, d, 64);   // group sum

    // np rounding grid: d = fl(fl(A - 2B) + C)
    float Bf = (float)s;
    float d32 = (A32 - 2.0f * Bf) + C32[mycand];
    unsigned u = __float_as_uint(d32);
    u = (u & 0x80000000u) ? ~u : (u | 0x80000000u);
    unsigned long long dk = ((unsigned long long)u << 32) | mycand;
#pragma unroll
    for (int d = 16; d < 64; d <<= 1) {                           // cross-group argmin
        unsigned long long o = __shfl_xor(dk, d, 64);
        dk = o < dk ? o : dk;
    }
    const unsigned ibest = (unsigned)(dk & 0xFFFFFFFFull);

    // winner broadcast: winning group's registers -> LDS (candidates unique,
    // exactly one group matches)
    if (mycand == ibest) {
#pragma unroll
        for (int it = 0; it < 8; ++it) ((float4*)zqs[wv])[j + it * 16] = ev[it];
    }
    __syncthreads();

    float4 wa = ((const float4*)zqs[wv])[t * 2];
    float4 wb = ((const float4*)zqs[wv])[t * 2 + 1];
    float4* op = (float4*)(out + (size_t)r * DIMV);
    op[t * 2] = wa;
    op[t * 2 + 1] = wb;
    double dx0 = (double)za.x - wa.x, dx1 = (double)za.y - wa.y;
    double dx2 = (double)za.z - wa.z, dx3 = (double)za.w - wa.w;
    double dx4 = (double)zb.x - wb.x, dx5 = (double)zb.y - wb.y;
    double dx6 = (double)zb.z - wb.z, dx7 = (double)zb.w - wb.w;
    double ls = dx0 * dx0 + dx1 * dx1 + dx2 * dx2 + dx3 * dx3 +
                dx4 * dx4 + dx5 * dx5 + dx6 * dx6 + dx7 * dx7;
#pragma unroll
    for (int d = 1; d < 64; d <<= 1) ls += __shfl_xor(ls, d, 64);
    if (t == 0) {
        out[IDX_OFF + r] = (float)ibest;
        rloss[r] = ls;
        atomicAdd(&counts[ibest], 1u);
    }
}

// ---------------- scalars: vq_loss (reduce rloss) + perplexity. Separate
// dispatch: the kernel boundary is the (free) device-scope coherence point —
// r9 showed per-block __threadfence costs ~500us here.
__global__ __launch_bounds__(1024) void scalars_k(
    const unsigned* __restrict__ counts,
    const double* __restrict__ rloss, float* __restrict__ out) {
    int t = threadIdx.x;   // 1024
    double ls = 0.0;
    for (int i = t; i < NTOK; i += 1024) ls += rloss[i];
#pragma unroll
    for (int d = 1; d < 64; d <<= 1) ls += __shfl_xor(ls, d, 64);
    float s = 0.0f;
    for (int i = t; i < KCODE; i += 1024) {
        float p = (float)counts[i] * (1.0f / (float)NTOK);
        s += p * logf(p + 1e-10f);
    }
#pragma unroll
    for (int d = 1; d < 64; d <<= 1) s += __shfl_xor(s, d, 64);
    __shared__ float red[16];
    __shared__ double redd[16];
    if ((t & 63) == 0) { red[t >> 6] = s; redd[t >> 6] = ls; }
    __syncthreads();
    if (t == 0) {
        float stot = 0.0f;
        double ltot = 0.0;
#pragma unroll
        for (int i = 0; i < 16; ++i) { stot += red[i]; ltot += redd[i]; }
        out[PERPO] = expf(-stot);
        out[LOSSO] = 0.25f * (float)(ltot * (1.0 / (double)(NTOK * DIMV)));
    }
}

extern "C" void kernel_launch(void* const* d_in, const int* in_sizes, int n_in,
                              void* d_out, int out_size, void* d_ws, size_t ws_size,
                              hipStream_t stream) {
    const float* z     = (const float*)d_in[0];
    const float* embed = (const float*)d_in[1];
    float* out = (float*)d_out;
    char* ws = (char*)d_ws;

    _Float16* A2 = (_Float16*)(ws + A2_OFF);
    _Float16* B2 = (_Float16*)(ws + B2_OFF);
    float* C32 = (float*)(ws + EN_OFF);
    unsigned* rk2 = (unsigned*)(ws + RK_OFF);
    unsigned* counts = (unsigned*)(ws + CNT_OFF);
    double* rloss = (double*)(ws + RLOSS_OFF);

    prep_k<<<5120, 256, 0, stream>>>(z, embed, A2, B2, C32, counts);
    gemm_top2_k<<<dim3(16, 128), 512, 0, stream>>>(A2, B2, C32, rk2);
    refine_k<<<NTOK / 4, 256, 0, stream>>>(rk2, embed, z, C32, out, counts, rloss);
    scalars_k<<<1, 1024, 0, stream>>>(counts, rloss, out);
}